// Round 3
// baseline (100381.805 us; speedup 1.0000x reference)
//
#include <hip/hip_runtime.h>
#include <cstddef>

#define TSEQ 256
#define NB   128
#define HID  512
#define G3   1536
#define INDIM 768
#define CH   16

typedef unsigned short bfraw;
using short8 = __attribute__((ext_vector_type(8))) short;
using f32x4  = __attribute__((ext_vector_type(4))) float;

__device__ __forceinline__ float bf2f(unsigned int u){ return __uint_as_float(u<<16); }
__device__ __forceinline__ bfraw f2bf(float f){
  unsigned int u = __float_as_uint(f);
  u += 0x7fffu + ((u>>16)&1u);
  return (bfraw)(u>>16);
}
__device__ __forceinline__ float fsig(float x){
  return __builtin_amdgcn_rcpf(1.0f + __expf(-x));
}
__device__ __forceinline__ float ftanh(float x){
  return 1.0f - 2.0f*__builtin_amdgcn_rcpf(1.0f + __expf(2.0f*x));
}

// ---------------- fp32 -> bf16 convert (n mult of 4) ----------------
__global__ void cvt_k(const float* __restrict__ in, bfraw* __restrict__ out, int n){
  int i = (blockIdx.x*256 + threadIdx.x)*4;
  if (i >= n) return;
  float4 v = *(const float4*)(in+i);
  uint2 o;
  o.x = (unsigned)f2bf(v.x) | ((unsigned)f2bf(v.y)<<16);
  o.y = (unsigned)f2bf(v.z) | ((unsigned)f2bf(v.w)<<16);
  *(uint2*)(out+i) = o;
}

// ---------------- transpose+convert: in fp32 [R][Cc] -> out bf16 [Cc][R] ------
__global__ __launch_bounds__(256)
void tconv_k(const float* __restrict__ in, bfraw* __restrict__ out, int R, int Cc){
  __shared__ float t[32][33];
  int c0 = blockIdx.x*32, r0 = blockIdx.y*32;
  int tx = threadIdx.x&31, ty = threadIdx.x>>5;
  #pragma unroll
  for (int i=0;i<32;i+=8) t[ty+i][tx] = in[(size_t)(r0+ty+i)*Cc + c0+tx];
  __syncthreads();
  #pragma unroll
  for (int i=0;i<32;i+=8) out[(size_t)(c0+ty+i)*R + r0+tx] = f2bf(t[tx][ty+i]);
}

// b_out[g] = bih[g] + sum_e Wih[g,e]*pb[e]   (all fp32)
__global__ void fuse_bias_k(const float* __restrict__ Wih, const float* __restrict__ bih,
                            const float* __restrict__ pb, float* __restrict__ bout)
{
  int g = blockIdx.x*256 + threadIdx.x;
  if (g >= G3) return;
  float acc = bih[g];
  const float* w = Wih + (size_t)g*HID;
  for (int e=0;e<HID;e+=4){
    float4 wv = *(const float4*)(w+e);
    float4 pv = *(const float4*)(pb+e);
    acc += wv.x*pv.x + wv.y*pv.y + wv.z*pv.z + wv.w*pv.w;
  }
  bout[g] = acc;
}

// ---------------- MFMA bf16 GEMM: C[MxN] = A[MxK] * B^T (+bias) --------------
// B is [N][K] row-major bf16. A fp32 (converted in staging) or bf16.
// 128x128 tile, BK=32, 4 waves, each wave 64x64 (4x4 frags of 16x16x32).
template<typename TA, typename TC, bool BIAS>
__global__ __launch_bounds__(256)
void mgemm(const TA* __restrict__ A, const bfraw* __restrict__ B,
           const float* __restrict__ bias, TC* __restrict__ C,
           int K, int lda, int ldb, int ldc)
{
  __shared__ bfraw Al[128*40];   // stride 40 bf16 = 80 B (16B-aligned rows, conflict-light)
  __shared__ bfraw Bl[128*40];
  const int tid = threadIdx.x;
  const size_t m0 = (size_t)blockIdx.y*128, n0 = (size_t)blockIdx.x*128;
  const int w = tid>>6, l = tid&63;
  const int wr = (w>>1)*64, wc = (w&1)*64;
  const int fr = l&15, fg = l>>4;      // frag row/col, k-group
  f32x4 acc[4][4];
  #pragma unroll
  for (int i=0;i<4;++i)
    #pragma unroll
    for (int j=0;j<4;++j) acc[i][j] = (f32x4){0.f,0.f,0.f,0.f};

  const int srow = tid>>1, skc = (tid&1)*16;
  for (int k0=0; k0<K; k0+=32){
    // stage A (convert if fp32)
    if constexpr (sizeof(TA)==4){
      const float* ap = (const float*)A + (m0+srow)*lda + k0 + skc;
      float4 v0=*(const float4*)ap, v1=*(const float4*)(ap+4),
             v2=*(const float4*)(ap+8), v3=*(const float4*)(ap+12);
      uint4 w0, w1;
      w0.x=(unsigned)f2bf(v0.x)|((unsigned)f2bf(v0.y)<<16);
      w0.y=(unsigned)f2bf(v0.z)|((unsigned)f2bf(v0.w)<<16);
      w0.z=(unsigned)f2bf(v1.x)|((unsigned)f2bf(v1.y)<<16);
      w0.w=(unsigned)f2bf(v1.z)|((unsigned)f2bf(v1.w)<<16);
      w1.x=(unsigned)f2bf(v2.x)|((unsigned)f2bf(v2.y)<<16);
      w1.y=(unsigned)f2bf(v2.z)|((unsigned)f2bf(v2.w)<<16);
      w1.z=(unsigned)f2bf(v3.x)|((unsigned)f2bf(v3.y)<<16);
      w1.w=(unsigned)f2bf(v3.z)|((unsigned)f2bf(v3.w)<<16);
      *(uint4*)&Al[srow*40+skc]   = w0;
      *(uint4*)&Al[srow*40+skc+8] = w1;
    } else {
      const bfraw* ap = (const bfraw*)A + (m0+srow)*lda + k0 + skc;
      *(uint4*)&Al[srow*40+skc]   = *(const uint4*)ap;
      *(uint4*)&Al[srow*40+skc+8] = *(const uint4*)(ap+8);
    }
    // stage B (always bf16 [n][k])
    {
      const bfraw* bp = B + (n0+srow)*ldb + k0 + skc;
      *(uint4*)&Bl[srow*40+skc]   = *(const uint4*)bp;
      *(uint4*)&Bl[srow*40+skc+8] = *(const uint4*)(bp+8);
    }
    __syncthreads();
    short8 af[4], bfr[4];
    #pragma unroll
    for (int i=0;i<4;++i) af[i]  = *(const short8*)&Al[(wr+i*16+fr)*40 + fg*8];
    #pragma unroll
    for (int j=0;j<4;++j) bfr[j] = *(const short8*)&Bl[(wc+j*16+fr)*40 + fg*8];
    #pragma unroll
    for (int i=0;i<4;++i)
      #pragma unroll
      for (int j=0;j<4;++j)
        acc[i][j] = __builtin_amdgcn_mfma_f32_16x16x32_bf16(af[i], bfr[j], acc[i][j], 0,0,0);
    __syncthreads();
  }
  // epilogue: C/D layout col=lane&15, row=(lane>>4)*4+reg  [verified]
  #pragma unroll
  for (int i=0;i<4;++i){
    #pragma unroll
    for (int j=0;j<4;++j){
      size_t n = n0 + wc + j*16 + fr;
      float bv = BIAS ? bias[n] : 0.f;
      #pragma unroll
      for (int r=0;r<4;++r){
        size_t m = m0 + wr + i*16 + fg*4 + r;
        float v = acc[i][j][r] + bv;
        if constexpr (sizeof(TC)==2) ((bfraw*)C)[m*ldc + n] = f2bf(v);
        else                         ((float*)C)[m*ldc + n] = v;
      }
    }
  }
}

// ---------------- GRU step (both GRUs via z). block 512 = 16b x 32d ----------
__global__ __launch_bounds__(512)
void gru_step_k(const float* __restrict__ GIp_t, const float* __restrict__ GIh_t,
                const bfraw* __restrict__ Whhp_bf, const bfraw* __restrict__ Whhh_bf,
                const float* __restrict__ bhh_p, const float* __restrict__ bhh_h,
                const float* __restrict__ hprev_p, const float* __restrict__ hprev_h,
                float* __restrict__ hcur_p, float* __restrict__ hcur_h,
                bfraw* __restrict__ op_t, bfraw* __restrict__ oh_t, int is_first)
{
  const int z = blockIdx.z;
  const float* GI  = z ? GIh_t   : GIp_t;
  const bfraw* Whh = z ? Whhh_bf : Whhp_bf;
  const float* bhh = z ? bhh_h   : bhh_p;
  const float* hpv = z ? hprev_h : hprev_p;
  float* hcur      = z ? hcur_h  : hcur_p;
  bfraw* obf       = z ? oh_t    : op_t;

  __shared__ float sh[16][HID];   // 32 KB
  const int tid = threadIdx.x;
  const int b0 = blockIdx.y * 16;
  #pragma unroll
  for (int i=0;i<16;++i){
    int l2 = tid + i*512;
    int r = l2 >> 9, c = l2 & 511;
    sh[r][c] = is_first ? 1.0f : hpv[(size_t)(b0+r)*HID + c];
  }
  __syncthreads();
  const int dl = tid & 31, bl = tid >> 5;
  const int d = blockIdx.x*32 + dl;
  const int b = b0 + bl;
  float ar = bhh[d], az = bhh[d+HID], an = bhh[d+2*HID];
  const bfraw* wr_ = Whh + (size_t)d*HID;
  const bfraw* wz_ = Whh + (size_t)(d+HID)*HID;
  const bfraw* wn_ = Whh + (size_t)(d+2*HID)*HID;
  const float* hb = sh[bl];
  for (int k=0;k<HID;k+=4){
    float4 h4 = *(const float4*)(hb+k);
    uint2 u0 = *(const uint2*)(wr_+k);
    uint2 u1 = *(const uint2*)(wz_+k);
    uint2 u2 = *(const uint2*)(wn_+k);
    ar += h4.x*bf2f(u0.x&0xffffu) + h4.y*bf2f(u0.x>>16) + h4.z*bf2f(u0.y&0xffffu) + h4.w*bf2f(u0.y>>16);
    az += h4.x*bf2f(u1.x&0xffffu) + h4.y*bf2f(u1.x>>16) + h4.z*bf2f(u1.y&0xffffu) + h4.w*bf2f(u1.y>>16);
    an += h4.x*bf2f(u2.x&0xffffu) + h4.y*bf2f(u2.x>>16) + h4.z*bf2f(u2.y&0xffffu) + h4.w*bf2f(u2.y>>16);
  }
  const float* gi = GI + (size_t)b*G3;
  float r  = fsig(gi[d] + ar);
  float zz = fsig(gi[d+HID] + az);
  float n  = ftanh(gi[d+2*HID] + r*an);
  float hp = hb[d];
  float hv = (1.0f-zz)*n + zz*hp;
  hcur[(size_t)b*HID + d] = hv;
  obf [(size_t)b*HID + d] = f2bf(hv);
}

// ---------------- cbuf[b,e] = o_h[t]@W_t + hm@W_m. block 512 = 8b x 64e ------
__global__ __launch_bounds__(512)
void wm_k(const float* __restrict__ hm, const bfraw* __restrict__ oh_t,
          const bfraw* __restrict__ Wt_bf, const bfraw* __restrict__ Wm_bf,
          float* __restrict__ cbuf, int is_first)
{
  __shared__ float shm[8][HID];
  __shared__ float sht[8][HID];
  const int tid = threadIdx.x;
  const int b0 = blockIdx.y*8;
  #pragma unroll
  for (int i=0;i<8;++i){
    int l2 = tid + i*512;
    int r = l2 >> 9, c = l2 & 511;
    shm[r][c] = is_first ? 1.0f : hm[(size_t)(b0+r)*HID + c];
    sht[r][c] = bf2f(oh_t[(size_t)(b0+r)*HID + c]);
  }
  __syncthreads();
  const int el = tid & 63, bl = tid >> 6;
  const int e = blockIdx.x*64 + el;
  const int b = b0 + bl;
  float acc = 0.f;
  const float* h = shm[bl];
  const float* x = sht[bl];
  #pragma unroll 4
  for (int dd=0; dd<HID; ++dd){
    acc = fmaf(x[dd], bf2f((unsigned)Wt_bf[(size_t)dd*HID + e]), acc);
    acc = fmaf(h[dd], bf2f((unsigned)Wm_bf[(size_t)dd*HID + e]), acc);
  }
  cbuf[(size_t)b*HID + e] = acc;
}

// ---------------- attention per-b: logits -> softmax -> a_t. block 1024 ------
__global__ __launch_bounds__(1024)
void att_k(const bfraw* __restrict__ Whs, const bfraw* __restrict__ o_p,
           const float* __restrict__ cbuf, const float* __restrict__ w_e,
           float* __restrict__ a_t)
{
  __shared__ float c_s[HID];
  __shared__ float we_s[HID];
  __shared__ float l_s[TSEQ];
  __shared__ float red[16];
  __shared__ float part[2][HID];
  const int tid = threadIdx.x;
  const int b = blockIdx.x;
  if (tid < HID){ c_s[tid] = cbuf[(size_t)b*HID + tid]; we_s[tid] = w_e[tid]; }
  __syncthreads();
  const int wv = tid >> 6, lane = tid & 63;
  // logits: wave wv owns t' in [wv*16, wv*16+16)
  #pragma unroll 2
  for (int i=0;i<16;++i){
    int t = wv*16 + i;
    const bfraw* row = Whs + ((size_t)t*NB + b)*HID;
    float s = 0.f;
    #pragma unroll
    for (int j=0;j<4;++j){
      int d0 = j*128 + lane*2;
      unsigned u = *(const unsigned*)(row + d0);
      s += ftanh(bf2f(u&0xffffu) + c_s[d0])   * we_s[d0];
      s += ftanh(bf2f(u>>16)     + c_s[d0+1]) * we_s[d0+1];
    }
    #pragma unroll
    for (int off=32; off; off>>=1) s += __shfl_xor(s, off);
    if (lane==0) l_s[t] = s;
  }
  __syncthreads();
  // softmax over 256 logits (first 4 waves)
  float v = -1e30f, e = 0.f;
  if (tid < TSEQ){
    v = l_s[tid];
    float m = v;
    #pragma unroll
    for (int off=32; off; off>>=1) m = fmaxf(m, __shfl_xor(m, off));
    if (lane==0) red[tid>>6] = m;
  }
  __syncthreads();
  float mx = fmaxf(fmaxf(red[0],red[1]), fmaxf(red[2],red[3]));
  if (tid < TSEQ){
    e = __expf(v - mx);
    float s = e;
    #pragma unroll
    for (int off=32; off; off>>=1) s += __shfl_xor(s, off);
    if (lane==0) red[8+(tid>>6)] = s;
  }
  __syncthreads();
  float S = red[8]+red[9]+red[10]+red[11];
  if (tid < TSEQ) l_s[tid] = e * __builtin_amdgcn_rcpf(S);
  __syncthreads();
  // a_t: thread -> (d = tid&511, t-half = tid>>9)
  const int d = tid & 511, th = tid >> 9;
  float acc = 0.f;
  #pragma unroll 4
  for (int t=th*128; t<th*128+128; ++t)
    acc = fmaf(l_s[t], bf2f((unsigned)o_p[((size_t)t*NB + b)*HID + d]), acc);
  part[th][d] = acc;
  __syncthreads();
  if (tid < HID) a_t[(size_t)b*HID + tid] = part[0][tid] + part[1][tid];
}

// ---------------- match-GRU cell. block 512 = 16b x 32d ----------------------
__global__ __launch_bounds__(512)
void cell_k(const bfraw* __restrict__ oh_t, const float* __restrict__ a_t,
            const float* __restrict__ hm_in, const bfraw* __restrict__ mWih_bf,
            const bfraw* __restrict__ mWhh_bf, const float* __restrict__ m_bih,
            const float* __restrict__ m_bhh, float* __restrict__ hm_out,
            int is_first)
{
  __shared__ bfraw sa[16][HID];
  __shared__ bfraw sx[16][HID];
  __shared__ bfraw sh[16][HID];   // 48 KB total
  const int tid = threadIdx.x;
  const int b0 = blockIdx.y*16;
  #pragma unroll
  for (int i=0;i<16;++i){
    int l2 = tid + i*512;
    int r = l2 >> 9, c = l2 & 511;
    sa[r][c] = f2bf(a_t[(size_t)(b0+r)*HID + c]);
    sx[r][c] = oh_t[(size_t)(b0+r)*HID + c];
    sh[r][c] = is_first ? (bfraw)0x3f80 : f2bf(hm_in[(size_t)(b0+r)*HID + c]);
  }
  __syncthreads();
  const int dl = tid & 31, bl = tid >> 5;
  const int d = blockIdx.x*32 + dl;
  const int b = b0 + bl;
  float gir = m_bih[d], giz = m_bih[d+HID], gin = m_bih[d+2*HID];
  float ghr = m_bhh[d], ghz = m_bhh[d+HID], ghn = m_bhh[d+2*HID];
  const bfraw* wir = mWih_bf + (size_t)d*1024;
  const bfraw* wiz = mWih_bf + (size_t)(d+HID)*1024;
  const bfraw* win = mWih_bf + (size_t)(d+2*HID)*1024;
  const bfraw* whr = mWhh_bf + (size_t)d*HID;
  const bfraw* whz = mWhh_bf + (size_t)(d+HID)*HID;
  const bfraw* whn = mWhh_bf + (size_t)(d+2*HID)*HID;
  const bfraw* av = sa[bl];
  const bfraw* xv = sx[bl];
  const bfraw* hv = sh[bl];
  for (int k=0;k<HID;k+=4){
    uint2 ua = *(const uint2*)(av+k);
    uint2 ux = *(const uint2*)(xv+k);
    uint2 uh = *(const uint2*)(hv+k);
    float a0=bf2f(ua.x&0xffffu), a1=bf2f(ua.x>>16), a2=bf2f(ua.y&0xffffu), a3=bf2f(ua.y>>16);
    float x0=bf2f(ux.x&0xffffu), x1=bf2f(ux.x>>16), x2=bf2f(ux.y&0xffffu), x3=bf2f(ux.y>>16);
    float h0=bf2f(uh.x&0xffffu), h1=bf2f(uh.x>>16), h2=bf2f(uh.y&0xffffu), h3=bf2f(uh.y>>16);
    uint2 u;
    u = *(const uint2*)(wir+k);     gir += a0*bf2f(u.x&0xffffu)+a1*bf2f(u.x>>16)+a2*bf2f(u.y&0xffffu)+a3*bf2f(u.y>>16);
    u = *(const uint2*)(wir+HID+k); gir += x0*bf2f(u.x&0xffffu)+x1*bf2f(u.x>>16)+x2*bf2f(u.y&0xffffu)+x3*bf2f(u.y>>16);
    u = *(const uint2*)(wiz+k);     giz += a0*bf2f(u.x&0xffffu)+a1*bf2f(u.x>>16)+a2*bf2f(u.y&0xffffu)+a3*bf2f(u.y>>16);
    u = *(const uint2*)(wiz+HID+k); giz += x0*bf2f(u.x&0xffffu)+x1*bf2f(u.x>>16)+x2*bf2f(u.y&0xffffu)+x3*bf2f(u.y>>16);
    u = *(const uint2*)(win+k);     gin += a0*bf2f(u.x&0xffffu)+a1*bf2f(u.x>>16)+a2*bf2f(u.y&0xffffu)+a3*bf2f(u.y>>16);
    u = *(const uint2*)(win+HID+k); gin += x0*bf2f(u.x&0xffffu)+x1*bf2f(u.x>>16)+x2*bf2f(u.y&0xffffu)+x3*bf2f(u.y>>16);
    u = *(const uint2*)(whr+k);     ghr += h0*bf2f(u.x&0xffffu)+h1*bf2f(u.x>>16)+h2*bf2f(u.y&0xffffu)+h3*bf2f(u.y>>16);
    u = *(const uint2*)(whz+k);     ghz += h0*bf2f(u.x&0xffffu)+h1*bf2f(u.x>>16)+h2*bf2f(u.y&0xffffu)+h3*bf2f(u.y>>16);
    u = *(const uint2*)(whn+k);     ghn += h0*bf2f(u.x&0xffffu)+h1*bf2f(u.x>>16)+h2*bf2f(u.y&0xffffu)+h3*bf2f(u.y>>16);
  }
  float r  = fsig(gir + ghr);
  float zz = fsig(giz + ghz);
  float n  = ftanh(gin + r*ghn);
  float hp = is_first ? 1.0f : hm_in[(size_t)b*HID + d];   // exact fp32 state path
  hm_out[(size_t)b*HID + d] = (1.0f-zz)*n + zz*hp;
}

__global__ void out_k(const float* __restrict__ hm, const float* __restrict__ oW,
                      const float* __restrict__ ob, float* __restrict__ out)
{
  int tid = threadIdx.x;
  if (tid >= NB*3) return;
  int b = tid / 3, c = tid % 3;
  float acc = ob[c];
  const float* h = hm + (size_t)b*HID;
  const float* w = oW + (size_t)c*HID;
  for (int d2=0; d2<HID; ++d2) acc = fmaf(h[d2], w[d2], acc);
  out[tid] = fmaxf(acc, 0.f);
}

extern "C" void kernel_launch(void* const* d_in, const int* in_sizes, int n_in,
                              void* d_out, int out_size, void* d_ws, size_t ws_size,
                              hipStream_t stream)
{
  const float* Ep    = (const float*)d_in[0];
  const float* Eh    = (const float*)d_in[1];
  const float* p_W   = (const float*)d_in[2];
  const float* p_b   = (const float*)d_in[3];
  const float* h_W   = (const float*)d_in[4];
  const float* h_b   = (const float*)d_in[5];
  const float* pgWih = (const float*)d_in[6];
  const float* pgWhh = (const float*)d_in[7];
  const float* pgbih = (const float*)d_in[8];
  const float* pgbhh = (const float*)d_in[9];
  const float* hgWih = (const float*)d_in[10];
  const float* hgWhh = (const float*)d_in[11];
  const float* hgbih = (const float*)d_in[12];
  const float* hgbhh = (const float*)d_in[13];
  const float* W_s   = (const float*)d_in[14];
  const float* W_t   = (const float*)d_in[15];
  const float* w_e   = (const float*)d_in[16];
  const float* W_m   = (const float*)d_in[17];
  const float* mWih  = (const float*)d_in[18];
  const float* mWhh  = (const float*)d_in[19];
  const float* mbih  = (const float*)d_in[20];
  const float* mbhh  = (const float*)d_in[21];
  const float* outW  = (const float*)d_in[22];
  const float* outb  = (const float*)d_in[23];

  const size_t OB     = (size_t)TSEQ*NB*HID*sizeof(bfraw);     // 33,554,432
  const size_t RB     = OB;                                     // max(GI chunks 25.2MB, Whs 33.5MB)
  const size_t WFB    = (size_t)G3*INDIM*sizeof(bfraw);         // 2,359,296
  const size_t PWTB   = (size_t)INDIM*HID*sizeof(bfraw);        // 786,432
  const size_t SQB    = (size_t)HID*HID*sizeof(bfraw);          // 524,288
  const size_t WHHB   = (size_t)G3*HID*sizeof(bfraw);           // 1,572,864
  const size_t MWIHB  = (size_t)G3*1024*sizeof(bfraw);          // 3,145,728
  const size_t BIASB  = (size_t)G3*sizeof(float);               // 6,144
  const size_t STATEB = (size_t)NB*HID*sizeof(float);           // 262,144
  const size_t needed = 2*OB + RB + 2*WFB + 2*PWTB + 3*SQB + 2*WHHB + MWIHB + WHHB + 2*BIASB + 8*STATEB;
  if (ws_size < needed) return;

  char* p = (char*)d_ws;
  bfraw* o_p_bf  = (bfraw*)p; p += OB;
  bfraw* o_h_bf  = (bfraw*)p; p += OB;
  char*  Rreg    = p;         p += RB;
  bfraw* Wfp_bf  = (bfraw*)p; p += WFB;
  bfraw* Wfh_bf  = (bfraw*)p; p += WFB;
  bfraw* pWT_bf  = (bfraw*)p; p += PWTB;
  bfraw* hWT_bf  = (bfraw*)p; p += PWTB;
  bfraw* WsT_bf  = (bfraw*)p; p += SQB;
  bfraw* Wt_bf   = (bfraw*)p; p += SQB;
  bfraw* Wm_bf   = (bfraw*)p; p += SQB;
  bfraw* Whhp_bf = (bfraw*)p; p += WHHB;
  bfraw* Whhh_bf = (bfraw*)p; p += WHHB;
  bfraw* mWih_bf = (bfraw*)p; p += MWIHB;
  bfraw* mWhh_bf = (bfraw*)p; p += WHHB;
  float* bfp     = (float*)p; p += BIASB;
  float* bfh     = (float*)p; p += BIASB;
  float* hsp0 = (float*)p; p += STATEB;
  float* hsp1 = (float*)p; p += STATEB;
  float* hsh0 = (float*)p; p += STATEB;
  float* hsh1 = (float*)p; p += STATEB;
  float* hm0  = (float*)p; p += STATEB;
  float* hm1  = (float*)p; p += STATEB;
  float* atb  = (float*)p; p += STATEB;
  float* cbuf = (float*)p; p += STATEB;

  float* GIp_c  = (float*)Rreg;                              // CH*NB x G3 fp32
  float* GIh_c  = (float*)(Rreg + (size_t)CH*NB*G3*sizeof(float));
  bfraw* Whs_bf = (bfraw*)Rreg;                              // phase C/D overlay

  dim3 b256(256), b512(512);

  // ---- Phase A: weight prep ----
  tconv_k<<<dim3(INDIM/32, HID/32), b256, 0, stream>>>(p_W, pWT_bf, HID, INDIM);   // [768][512]
  tconv_k<<<dim3(INDIM/32, HID/32), b256, 0, stream>>>(h_W, hWT_bf, HID, INDIM);
  tconv_k<<<dim3(HID/32, HID/32),  b256, 0, stream>>>(W_s, WsT_bf, HID, HID);      // [n][k]
  cvt_k<<<dim3((HID*HID)/1024),  b256, 0, stream>>>(W_t,  Wt_bf,  HID*HID);
  cvt_k<<<dim3((HID*HID)/1024),  b256, 0, stream>>>(W_m,  Wm_bf,  HID*HID);
  cvt_k<<<dim3((G3*HID)/1024),   b256, 0, stream>>>(pgWhh, Whhp_bf, G3*HID);
  cvt_k<<<dim3((G3*HID)/1024),   b256, 0, stream>>>(hgWhh, Whhh_bf, G3*HID);
  cvt_k<<<dim3((G3*1024)/1024),  b256, 0, stream>>>(mWih,  mWih_bf, G3*1024);
  cvt_k<<<dim3((G3*HID)/1024),   b256, 0, stream>>>(mWhh,  mWhh_bf, G3*HID);
  fuse_bias_k<<<dim3(G3/256), b256, 0, stream>>>(pgWih, pgbih, p_b, bfp);
  fuse_bias_k<<<dim3(G3/256), b256, 0, stream>>>(hgWih, hgbih, h_b, bfh);
  // fold: Wf = Wih @ xW   (A = Wih fp32 [1536][512], B = xW^T bf16 [768][512])
  mgemm<float, bfraw, false><<<dim3(INDIM/128, G3/128), b256, 0, stream>>>(
    pgWih, pWT_bf, nullptr, Wfp_bf, HID, HID, HID, INDIM);
  mgemm<float, bfraw, false><<<dim3(INDIM/128, G3/128), b256, 0, stream>>>(
    hgWih, hWT_bf, nullptr, Wfh_bf, HID, HID, HID, INDIM);

  // ---- Phase B: chunked GI (MFMA) + GRU scans ----
  for (int c = 0; c < TSEQ/CH; ++c){
    mgemm<float, float, true><<<dim3(G3/128, (CH*NB)/128), b256, 0, stream>>>(
      Ep + (size_t)c*CH*NB*INDIM, Wfp_bf, bfp, GIp_c, INDIM, INDIM, INDIM, G3);
    mgemm<float, float, true><<<dim3(G3/128, (CH*NB)/128), b256, 0, stream>>>(
      Eh + (size_t)c*CH*NB*INDIM, Wfh_bf, bfh, GIh_c, INDIM, INDIM, INDIM, G3);
    for (int tt = 0; tt < CH; ++tt){
      int t = c*CH + tt;
      const float* hp_p = (t&1) ? hsp1 : hsp0;
      const float* hp_h = (t&1) ? hsh1 : hsh0;
      float* hc_p = (t&1) ? hsp0 : hsp1;
      float* hc_h = (t&1) ? hsh0 : hsh1;
      gru_step_k<<<dim3(16,8,2), b512, 0, stream>>>(
        GIp_c + (size_t)tt*NB*G3, GIh_c + (size_t)tt*NB*G3,
        Whhp_bf, Whhh_bf, pgbhh, hgbhh,
        hp_p, hp_h, hc_p, hc_h,
        o_p_bf + (size_t)t*NB*HID, o_h_bf + (size_t)t*NB*HID,
        (t==0)?1:0);
    }
  }

  // ---- Phase C: Whs = o_p @ W_s (MFMA, bf16 out; overlays GI region) ----
  mgemm<bfraw, bfraw, false><<<dim3(HID/128, (TSEQ*NB)/128), b256, 0, stream>>>(
    o_p_bf, WsT_bf, nullptr, Whs_bf, HID, HID, HID, HID);

  // ---- Phase D: attention-match scan ----
  for (int t = 0; t < TSEQ; ++t){
    float* hmi = (t&1) ? hm1 : hm0;
    float* hmo = (t&1) ? hm0 : hm1;
    int isf = (t==0)?1:0;
    const bfraw* oh_t = o_h_bf + (size_t)t*NB*HID;
    wm_k<<<dim3(8,16), b512, 0, stream>>>(hmi, oh_t, Wt_bf, Wm_bf, cbuf, isf);
    att_k<<<dim3(128), dim3(1024), 0, stream>>>(Whs_bf, o_p_bf, cbuf, w_e, atb);
    cell_k<<<dim3(16,8), b512, 0, stream>>>(oh_t, atb, hmi, mWih_bf, mWhh_bf, mbih, mbhh, hmo, isf);
  }

  // ---- Phase E ----
  out_k<<<dim3(1), dim3(384), 0, stream>>>(hm0, outW, outb, (float*)d_out);
}